// Round 9
// baseline (1173.462 us; speedup 1.0000x reference)
//
#include <hip/hip_runtime.h>
#include <hip/hip_bf16.h>
#include <hip/hip_cooperative_groups.h>

namespace cg = cooperative_groups;

typedef __hip_bfloat16 bf16;
typedef __attribute__((ext_vector_type(8))) short short8;
typedef __attribute__((ext_vector_type(4))) short s16x4;
typedef __attribute__((ext_vector_type(4))) float f32x4;

#define NTOK 512
#define TOTC 66832
#define CM_SZ 65536

__device__ __forceinline__ float b2f(bf16 x) { return __bfloat162float(x); }
__device__ __forceinline__ bf16 f2b(float x) { return __float2bfloat16(x); }
__device__ __forceinline__ float gelu_f(float x) {
  return 0.5f * x * (1.0f + erff(x * 0.7071067811865476f));
}
__device__ __forceinline__ f32x4 mfma16(short8 a, short8 b, f32x4 c) {
  return __builtin_amdgcn_mfma_f32_16x16x32_bf16(a, b, c, 0, 0, 0);
}

struct AllArgs {
  const float *te, *roi, *img;
  const float *g_off, *b_off, *w_off, *off_bias, *g_pg, *b_pg, *w_pg1, *b_pg1;
  const float *w_pg2, *b_pg2, *m_beta, *s_beta;
  const float *w_out, *b_out, *ln1_g, *ln1_b, *w_qkv, *b_qkv, *w_proj, *b_proj;
  const float *ln2_g, *ln2_b, *w_fc1, *b_fc1, *w_fc2, *b_fc2;
  bf16 *imgT, *tb16;
  int *meta_i;
  float *meta_w;
  bf16 *pchunk, *Sbuf, *h2;
  bf16 *w_outT, *w_qkvT, *w_projT, *w_fc1T, *w_fc2T;
  float *part, *x1, *xa, *qkvf;
  bf16 *ln1buf, *ln2buf, *obuf, *hfc;
  float *outf;
};

// ---------------- shared GEMM tile helper: A MxK rm bf16, BT NxK rm bf16 ----------------
__device__ __forceinline__ void gemm64(const bf16* A, const bf16* BT, int K,
                                       int nb, int mb, int k0, int kchunk,
                                       char* SM, int t, f32x4 acc[2][2]) {
  bf16 (*As)[72] = (bf16(*)[72])SM;
  bf16 (*Bs)[72] = (bf16(*)[72])(SM + 9216);
  int lane = t & 63, w = t >> 6;
  int quad = lane >> 4, l16 = lane & 15;
  int wm = (w >> 1) * 32, wn = (w & 1) * 32;
  int r = t >> 2, kk = (t & 3) * 16;
#pragma unroll
  for (int i = 0; i < 2; ++i)
#pragma unroll
    for (int j = 0; j < 2; ++j) acc[i][j] = (f32x4){0.f, 0.f, 0.f, 0.f};
  for (int kt = 0; kt < kchunk; kt += 64) {
    __syncthreads();
    const bf16* ga = A + (size_t)(mb * 64 + r) * K + k0 + kt + kk;
    *(short8*)&As[r][kk] = *(const short8*)ga;
    *(short8*)&As[r][kk + 8] = *(const short8*)(ga + 8);
    const bf16* gb = BT + (size_t)(nb * 64 + r) * K + k0 + kt + kk;
    *(short8*)&Bs[r][kk] = *(const short8*)gb;
    *(short8*)&Bs[r][kk + 8] = *(const short8*)(gb + 8);
    __syncthreads();
#pragma unroll
    for (int kss = 0; kss < 2; ++kss) {
      short8 af[2], bff[2];
#pragma unroll
      for (int mt = 0; mt < 2; ++mt)
        af[mt] = *(const short8*)&As[wm + mt * 16 + l16][kss * 32 + quad * 8];
#pragma unroll
      for (int nt = 0; nt < 2; ++nt)
        bff[nt] = *(const short8*)&Bs[wn + nt * 16 + l16][kss * 32 + quad * 8];
#pragma unroll
      for (int mt = 0; mt < 2; ++mt)
#pragma unroll
        for (int nt = 0; nt < 2; ++nt)
          acc[mt][nt] = mfma16(af[mt], bff[nt], acc[mt][nt]);
    }
  }
}

__device__ __forceinline__ void epi_ln_body(const AllArgs& A, int tok, int t, int S_,
                                            const float* bias, const float* res,
                                            const float* g, const float* bvec,
                                            float* xout, bf16* lnout, char* SM) {
  int lane = t & 63, w = t >> 6;
  float* wsum = (float*)SM;
  size_t base = (size_t)tok * 512;
  float a0 = bias[t] + res[base + t];
  float a1 = bias[t + 256] + res[base + t + 256];
  for (int sp = 0; sp < S_; ++sp) {
    const float* p = A.part + (size_t)sp * 262144 + base;
    a0 += p[t];
    a1 += p[t + 256];
  }
  xout[base + t] = a0;
  xout[base + t + 256] = a1;
  float s = a0 + a1;
#pragma unroll
  for (int o = 32; o; o >>= 1) s += __shfl_xor(s, o);
  if (lane == 0) wsum[w] = s;
  __syncthreads();
  float mean = (wsum[0] + wsum[1] + wsum[2] + wsum[3]) * (1.0f / 512.0f);
  float d0 = a0 - mean, d1 = a1 - mean;
  float ss = d0 * d0 + d1 * d1;
#pragma unroll
  for (int o = 32; o; o >>= 1) ss += __shfl_xor(ss, o);
  __syncthreads();
  if (lane == 0) wsum[w] = ss;
  __syncthreads();
  float var = (wsum[0] + wsum[1] + wsum[2] + wsum[3]) * (1.0f / 512.0f);
  float rstd = rsqrtf(var + 1e-5f);
  lnout[base + t] = f2b(d0 * rstd * g[t] + bvec[t]);
  lnout[base + t + 256] = f2b(d1 * rstd * g[t + 256] + bvec[t + 256]);
}

// ---------------- P0: prep [0,512) | img transpose [512,2560) | weight transpose [2560,10240) ----------------
__device__ void phase0(const AllArgs& A, int job, int t, char* SM) {
  int lane = t & 63, w = t >> 6;
  if (job < 512) {
    int tok = job;
    float* xo = (float*)SM;
    float* xq = xo + 512;
    float* offb = xq + 512;
    float* red = offb + 72;
    float* wsum = red + 4;
    size_t base = (size_t)tok * 512;
    float a0 = A.te[base + t];
    float a1 = A.te[base + t + 256];
    float s = a0 + a1;
#pragma unroll
    for (int o = 32; o; o >>= 1) s += __shfl_xor(s, o);
    if (lane == 0) wsum[w] = s;
    __syncthreads();
    float mean = (wsum[0] + wsum[1] + wsum[2] + wsum[3]) * (1.0f / 512.0f);
    float d0 = a0 - mean, d1 = a1 - mean;
    float ss = d0 * d0 + d1 * d1;
#pragma unroll
    for (int o = 32; o; o >>= 1) ss += __shfl_xor(ss, o);
    __syncthreads();
    if (lane == 0) wsum[w] = ss;
    __syncthreads();
    float var = (wsum[0] + wsum[1] + wsum[2] + wsum[3]) * (1.0f / 512.0f);
    float rstd = rsqrtf(var + 1e-5f);
    xo[t] = d0 * rstd * A.g_off[t] + A.b_off[t];
    xo[t + 256] = d1 * rstd * A.g_off[t + 256] + A.b_off[t + 256];
    xq[t] = d0 * rstd * A.g_pg[t] + A.b_pg[t];
    xq[t + 256] = d1 * rstd * A.g_pg[t + 256] + A.b_pg[t + 256];
    __syncthreads();
    if (t < 128) {
      float acc = A.b_pg1[t];
      for (int d = 0; d < 512; ++d) acc = fmaf(xq[d], A.w_pg1[d * 128 + t], acc);
      A.tb16[(size_t)tok * 128 + t] = f2b(acc);
    } else if (t < 200) {
      int j = t - 128;
      float acc = A.off_bias[j];
      for (int d = 0; d < 512; ++d) acc = fmaf(xo[d], A.w_off[d * 72 + j], acc);
      offb[j] = acc;
    }
    __syncthreads();
    if (t < 2) {
      float mu = 0.f;
      for (int p = 0; p < 36; ++p) mu += offb[p * 2 + t];
      mu *= (1.0f / 36.0f);
      float s2 = 0.f;
      for (int p = 0; p < 36; ++p) { float dd = offb[p * 2 + t] - mu; s2 += dd * dd; }
      float sd = sqrtf(s2 * (1.0f / 35.0f)) + 1e-5f;  // ddof=1, then +1e-5
      red[t] = mu;
      red[2 + t] = 1.0f / (3.0f * sd);
    }
    __syncthreads();
    if (t < 36) {
      int p = t;
      float r0 = A.roi[tok * 4 + 0], r1 = A.roi[tok * 4 + 1];
      float r2 = A.roi[tok * 4 + 2], r3 = A.roi[tok * 4 + 3];
      float cx = (r0 + r2) * 0.5f, cy = (r1 + r3) * 0.5f;
      float bw = r2 - r0, bh = r3 - r1;
      float ox = (offb[p * 2 + 0] - red[0]) * red[2];
      float oy = (offb[p * 2 + 1] - red[1]) * red[3];
      float fx = (cx + ox * bw) * 128.0f - 0.5f;
      float fy = (cy + oy * bh) * 128.0f - 0.5f;
      float x0f = floorf(fx), y0f = floorf(fy);
      float wx = fx - x0f, wy = fy - y0f;
      int x0 = min(max((int)x0f, 0), 127);
      int x1i = min(max((int)x0f + 1, 0), 127);
      int y0 = min(max((int)y0f, 0), 127);
      int y1i = min(max((int)y0f + 1, 0), 127);
      int ibase = (tok >> 6) * 16384;
      int mi = (tok * 36 + p) * 4;
      A.meta_i[mi + 0] = (ibase + y0 * 128 + x0) * 256;
      A.meta_i[mi + 1] = (ibase + y0 * 128 + x1i) * 256;
      A.meta_i[mi + 2] = (ibase + y1i * 128 + x0) * 256;
      A.meta_i[mi + 3] = (ibase + y1i * 128 + x1i) * 256;
      A.meta_w[mi + 0] = (1.f - wx) * (1.f - wy);
      A.meta_w[mi + 1] = wx * (1.f - wy);
      A.meta_w[mi + 2] = (1.f - wx) * wy;
      A.meta_w[mi + 3] = wx * wy;
    }
  } else if (job < 2560) {
    int bb = job - 512;
    int b = bb >> 8;
    int hw0 = (bb & 255) * 64;
    bf16 (*tl)[72] = (bf16(*)[72])SM;
    int hw_l = (t & 15) * 4;
#pragma unroll
    for (int pass = 0; pass < 16; ++pass) {
      int c = (t >> 4) + 16 * pass;
      const float4 v = *(const float4*)&A.img[((size_t)(b * 256 + c) << 14) + hw0 + hw_l];
      float vv[4] = {v.x, v.y, v.z, v.w};
      int mask = ((c >> 3) & 31) << 1;
      int base = hw_l ^ (mask & 60);
      int swp = mask & 2;
      bf16 o[4];
#pragma unroll
      for (int k = 0; k < 4; ++k) o[k] = f2b(vv[k ^ swp]);
      *(s16x4*)&tl[c][base] = *(const s16x4*)o;
    }
    __syncthreads();
    int c8 = (t & 31) * 8;
    int hwb = t >> 5;
    int rmask = ((c8 >> 3) & 31) << 1;
#pragma unroll
    for (int pass = 0; pass < 8; ++pass) {
      int hw = hwb + 8 * pass;
      bf16 tmp[8];
#pragma unroll
      for (int j = 0; j < 8; ++j) tmp[j] = tl[c8 + j][hw ^ rmask];
      *(short8*)&A.imgT[((size_t)(b << 14) + hw0 + hw) * 256 + c8] = *(const short8*)tmp;
    }
  } else {
    int b = job - 2560;
    const float* W;
    bf16* O;
    int K, N, loc;
    if (b < 4608) { W = A.w_out; O = A.w_outT; K = 9216; N = 512; loc = b; }
    else if (b < 5376) { W = A.w_qkv; O = A.w_qkvT; K = 512; N = 1536; loc = b - 4608; }
    else if (b < 5632) { W = A.w_proj; O = A.w_projT; K = 512; N = 512; loc = b - 5376; }
    else if (b < 6656) { W = A.w_fc1; O = A.w_fc1T; K = 512; N = 2048; loc = b - 5632; }
    else { W = A.w_fc2; O = A.w_fc2T; K = 2048; N = 512; loc = b - 6656; }
    int ntn = N >> 5;
    int nb = loc % ntn, kb = loc / ntn;
    int n0 = nb * 32, k0 = kb * 32;
    float (*tw)[33] = (float(*)[33])SM;
    int r = t >> 5, c = t & 31;
#pragma unroll
    for (int i = 0; i < 4; ++i)
      tw[r + 8 * i][c] = W[(size_t)(k0 + r + 8 * i) * N + n0 + c];
    __syncthreads();
    int n_l = t >> 3, k4 = (t & 7) * 4;
    bf16 tmp[4];
#pragma unroll
    for (int j = 0; j < 4; ++j) tmp[j] = f2b(tw[k4 + j][n_l]);
    *(s16x4*)&O[(size_t)(n0 + n_l) * K + k0 + k4] = *(const s16x4*)tmp;
  }
}

// ---------------- P1: pg2 MFMA [0,1045) | bilinear sample [1045,1557) ----------------
__device__ void phase1(const AllArgs& A, int job, int t, char* SM) {
  int lane = t & 63, w = t >> 6;
  int quad = lane >> 4, l16 = lane & 15;
  if (job < 1045) {
    bf16 (*BsT)[136] = (bf16(*)[136])SM;
    bf16 (*stg)[72] = (bf16(*)[72])(SM + 17408);
    int n0 = job * 64;
    {
      int nl = (t & 15) * 4, kk = t >> 4;
#pragma unroll
      for (int pass = 0; pass < 8; ++pass) {
        int k = kk + pass * 16;
        int n = n0 + nl;
        int nc = (n + 3 < TOTC) ? n : (TOTC - 4);
        const float4 v = *(const float4*)(A.w_pg2 + (size_t)k * TOTC + nc);
        BsT[nl + 0][k] = f2b(v.x);
        BsT[nl + 1][k] = f2b(v.y);
        BsT[nl + 2][k] = f2b(v.z);
        BsT[nl + 3][k] = f2b(v.w);
      }
    }
    __syncthreads();
    float bias_r[4];
#pragma unroll
    for (int nt = 0; nt < 4; ++nt) {
      int col = n0 + nt * 16 + l16;
      bias_r[nt] = (col < TOTC) ? A.b_pg2[col] : 0.f;
    }
    for (int half = 0; half < 2; ++half) {
      int row0 = half * 256;
      f32x4 acc[4][4];
#pragma unroll
      for (int i = 0; i < 4; ++i)
#pragma unroll
        for (int j = 0; j < 4; ++j) acc[i][j] = (f32x4){0.f, 0.f, 0.f, 0.f};
      const bf16* Abase = A.tb16 + ((size_t)(row0 + w * 64 + l16)) * 128 + quad * 8;
#pragma unroll
      for (int ks = 0; ks < 4; ++ks) {
        short8 af[4], bff[4];
#pragma unroll
        for (int mt = 0; mt < 4; ++mt)
          af[mt] = *(const short8*)(Abase + mt * 16 * 128 + ks * 32);
#pragma unroll
        for (int nt = 0; nt < 4; ++nt)
          bff[nt] = *(const short8*)(&BsT[nt * 16 + l16][ks * 32 + quad * 8]);
#pragma unroll
        for (int mt = 0; mt < 4; ++mt)
#pragma unroll
          for (int nt = 0; nt < 4; ++nt)
            acc[mt][nt] = mfma16(af[mt], bff[nt], acc[mt][nt]);
      }
#pragma unroll
      for (int mt = 0; mt < 4; ++mt) {
        __syncthreads();
#pragma unroll
        for (int nt = 0; nt < 4; ++nt)
#pragma unroll
          for (int r = 0; r < 4; ++r)
            stg[w * 16 + quad * 4 + r][nt * 16 + l16] =
                f2b(acc[mt][nt][r] + bias_r[nt]);
        __syncthreads();
#pragma unroll
        for (int pass = 0; pass < 2; ++pass) {
          int t2 = t + pass * 256;
          int row_l = t2 >> 3;
          int wi = row_l >> 4, rr = row_l & 15;
          int c8 = (t2 & 7) * 8;
          int col = n0 + c8;
          if (col < TOTC) {
            int grow = row0 + wi * 64 + mt * 16 + rr;
            *(short8*)&A.pchunk[(size_t)grow * TOTC + col] =
                *(const short8*)&stg[wi * 16 + rr][c8];
          }
        }
      }
      __syncthreads();
    }
  } else {
    int tok = job - 1045;
#pragma unroll 6
    for (int p = 0; p < 36; ++p) {
      int mi = (tok * 36 + p) * 4;
      int o00 = A.meta_i[mi + 0], o01 = A.meta_i[mi + 1];
      int o10 = A.meta_i[mi + 2], o11 = A.meta_i[mi + 3];
      float w00 = A.meta_w[mi + 0], w01 = A.meta_w[mi + 1];
      float w10 = A.meta_w[mi + 2], w11 = A.meta_w[mi + 3];
      float v = w00 * b2f(A.imgT[o00 + t]) + w01 * b2f(A.imgT[o01 + t]) +
                w10 * b2f(A.imgT[o10 + t]) + w11 * b2f(A.imgT[o11 + t]);
      A.Sbuf[((size_t)tok * 36 + p) * 256 + t] = f2b(v);
    }
  }
}

// ---------------- P2: mix3 (1024 jobs) ----------------
__device__ void phase2(const AllArgs& A, int job, int t, char* SM) {
  int lane = t & 63, w = t >> 6;
  int quad = lane >> 4, l16 = lane & 15;
  int tok = job & 511, dh = (job >> 9) * 128;
  bf16 (*h1T)[72] = (bf16(*)[72])SM;                 // [128][72]
  bf16 (*smS)[72] = (bf16(*)[72])(SM + 18432);       // [48][72]
  short (*cmw)[32][40] = (short(*)[32][40])(SM + 25344);  // [4][32][40]
  for (int i = t; i < 1728; i += 256) ((unsigned*)smS)[i] = 0u;
  __syncthreads();
  const bf16* sm = A.pchunk + (size_t)tok * TOTC + CM_SZ;
  for (int i = t; i < 1296; i += 256) {
    int q = i / 36, p = i - q * 36;
    smS[q][p] = sm[i];
  }
  f32x4 acc[3][2];
#pragma unroll
  for (int i = 0; i < 3; ++i)
#pragma unroll
    for (int j = 0; j < 2; ++j) acc[i][j] = (f32x4){0.f, 0.f, 0.f, 0.f};
  const bf16* Sg = A.Sbuf + (size_t)tok * 9216;
  const bf16* Cg = A.pchunk + (size_t)tok * TOTC;
  int dw = w * 32;
  int c_l = lane & 31;
  int dtop = (lane >> 5) * 16;
  const bf16* src0 = Cg + (size_t)c_l * 256 + dh + dw + dtop;
  short8 v0 = *(const short8*)src0;
  short8 v1 = *(const short8*)(src0 + 8);
#pragma unroll
  for (int kc = 0; kc < 256; kc += 32) {
#pragma unroll
    for (int j = 0; j < 8; ++j) cmw[w][dtop + j][c_l] = v0[j];
#pragma unroll
    for (int j = 0; j < 8; ++j) cmw[w][dtop + 8 + j][c_l] = v1[j];
    short8 a[3];
#pragma unroll
    for (int mt = 0; mt < 3; ++mt)
      a[mt] = *(const short8*)(Sg + (size_t)(mt * 16 + l16) * 256 + kc + quad * 8);
    short8 v0n, v1n;
    if (kc < 224) {
      const bf16* srcn = Cg + (size_t)(kc + 32 + c_l) * 256 + dh + dw + dtop;
      v0n = *(const short8*)srcn;
      v1n = *(const short8*)(srcn + 8);
    }
    asm volatile("" ::: "memory");
    short8 bfr[2];
#pragma unroll
    for (int nt = 0; nt < 2; ++nt)
      bfr[nt] = *(const short8*)&cmw[w][nt * 16 + l16][quad * 8];
#pragma unroll
    for (int mt = 0; mt < 3; ++mt)
#pragma unroll
      for (int nt = 0; nt < 2; ++nt)
        acc[mt][nt] = mfma16(a[mt], bfr[nt], acc[mt][nt]);
    asm volatile("" ::: "memory");
    v0 = v0n;
    v1 = v1n;
  }
#pragma unroll
  for (int nt = 0; nt < 2; ++nt) {
    int dl = dw + nt * 16 + l16;
    float mb = A.m_beta[dh + dl];
#pragma unroll
    for (int mt = 0; mt < 3; ++mt)
#pragma unroll
      for (int r = 0; r < 4; ++r) {
        int p = mt * 16 + quad * 4 + r;
        if (p < 36) h1T[dl][p] = f2b(gelu_f(acc[mt][nt][r] + mb));
      }
  }
  for (int i = t; i < 128 * 28; i += 256) {
    int d = i / 28, p = 36 + i % 28;
    h1T[d][p] = (bf16)0.f;
  }
  __syncthreads();
  f32x4 acc2[3][2];
#pragma unroll
  for (int i = 0; i < 3; ++i)
#pragma unroll
    for (int j = 0; j < 2; ++j) acc2[i][j] = (f32x4){0.f, 0.f, 0.f, 0.f};
#pragma unroll
  for (int ks = 0; ks < 2; ++ks) {
    short8 a2[3], b2v[2];
#pragma unroll
    for (int mt = 0; mt < 3; ++mt)
      a2[mt] = *(const short8*)&smS[mt * 16 + l16][ks * 32 + quad * 8];
#pragma unroll
    for (int nt = 0; nt < 2; ++nt)
      b2v[nt] = *(const short8*)&h1T[dw + nt * 16 + l16][ks * 32 + quad * 8];
#pragma unroll
    for (int mt = 0; mt < 3; ++mt)
#pragma unroll
      for (int nt = 0; nt < 2; ++nt)
        acc2[mt][nt] = mfma16(a2[mt], b2v[nt], acc2[mt][nt]);
  }
  bf16* h2p = A.h2 + (size_t)tok * 9216 + dh;
#pragma unroll
  for (int mt = 0; mt < 3; ++mt)
#pragma unroll
    for (int r = 0; r < 4; ++r) {
      int q = mt * 16 + quad * 4 + r;
      if (q >= 36) continue;
      float sb = A.s_beta[q];
#pragma unroll
      for (int nt = 0; nt < 2; ++nt)
        h2p[q * 256 + dw + nt * 16 + l16] = f2b(gelu_f(acc2[mt][nt][r] + sb));
    }
}

// ---------------- P3: w_out GEMM split-K=16 (1024 jobs) ----------------
__device__ void phase3(const AllArgs& A, int job, int t, char* SM) {
  int lane = t & 63, w = t >> 6;
  int quad = lane >> 4, l16 = lane & 15;
  int nb = job & 7, mb = (job >> 3) & 7, ks = job >> 6;
  f32x4 acc[2][2];
  gemm64(A.h2, A.w_outT, 9216, nb, mb, ks * 576, 576, SM, t, acc);
  int wm = (w >> 1) * 32, wn = (w & 1) * 32;
#pragma unroll
  for (int mt = 0; mt < 2; ++mt)
#pragma unroll
    for (int rr = 0; rr < 4; ++rr) {
      int m = mb * 64 + wm + mt * 16 + quad * 4 + rr;
#pragma unroll
      for (int nt = 0; nt < 2; ++nt) {
        int n = nb * 64 + wn + nt * 16 + l16;
        A.part[(size_t)ks * 262144 + (size_t)m * 512 + n] = acc[mt][nt][rr];
      }
    }
}

__device__ void phase4(const AllArgs& A, int job, int t, char* SM) {
  epi_ln_body(A, job, t, 16, A.b_out, A.te, A.ln1_g, A.ln1_b, A.x1, A.ln1buf, SM);
}

// ---------------- P5: qkv GEMM single-pass (192 jobs) ----------------
__device__ void phase5(const AllArgs& A, int job, int t, char* SM) {
  int lane = t & 63, w = t >> 6;
  int quad = lane >> 4, l16 = lane & 15;
  int nb = job % 24, mb = job / 24;
  f32x4 acc[2][2];
  gemm64(A.ln1buf, A.w_qkvT, 512, nb, mb, 0, 512, SM, t, acc);
  int wm = (w >> 1) * 32, wn = (w & 1) * 32;
#pragma unroll
  for (int mt = 0; mt < 2; ++mt)
#pragma unroll
    for (int rr = 0; rr < 4; ++rr) {
      int m = mb * 64 + wm + mt * 16 + quad * 4 + rr;
#pragma unroll
      for (int nt = 0; nt < 2; ++nt) {
        int n = nb * 64 + wn + nt * 16 + l16;
        A.qkvf[(size_t)m * 1536 + n] = acc[mt][nt][rr] + A.b_qkv[n];
      }
    }
}

// ---------------- P6: attention (256 jobs) ----------------
__device__ void phase6(const AllArgs& A, int job, int t, char* SM) {
  int lane = t & 63, w = t >> 6;
  int bh = job >> 2;
  int b = bh >> 3, h = bh & 7;
  int q0 = (job & 3) * 16;
  float (*kT)[65] = (float(*)[65])SM;
  float (*vT)[65] = (float(*)[65])(SM + 16640);
  float (*att)[65] = (float(*)[65])(SM + 33280);
#pragma unroll
  for (int i = 0; i < 16; ++i) {
    int idx = t + i * 256;
    int j = idx >> 6, d = idx & 63;
    size_t tb = (size_t)(b * 64 + j) * 1536 + h * 64 + d;
    kT[j][d] = A.qkvf[tb + 512];
    vT[j][d] = A.qkvf[tb + 1024];
  }
  __syncthreads();
#pragma unroll
  for (int m = 0; m < 4; ++m) {
    int il = w * 4 + m;
    int i = q0 + il;
    const float* qrow = &A.qkvf[(size_t)(b * 64 + i) * 1536 + h * 64];
    float s = 0.f;
    for (int d = 0; d < 64; ++d) s = fmaf(qrow[d], kT[lane][d], s);
    s *= 0.125f;
    float mx = s;
#pragma unroll
    for (int o = 32; o; o >>= 1) mx = fmaxf(mx, __shfl_xor(mx, o));
    float e = expf(s - mx);
    float sum = e;
#pragma unroll
    for (int o = 32; o; o >>= 1) sum += __shfl_xor(sum, o);
    att[il][lane] = e / sum;
  }
  __syncthreads();
#pragma unroll
  for (int m = 0; m < 4; ++m) {
    int il = w * 4 + m;
    int i = q0 + il;
    float o = 0.f;
    for (int j = 0; j < 64; ++j) o = fmaf(att[il][j], vT[j][lane], o);
    A.obuf[(size_t)(b * 64 + i) * 512 + h * 64 + lane] = f2b(o);
  }
}

// ---------------- P7: proj GEMM split-K=4 (256 jobs) ----------------
__device__ void phase7(const AllArgs& A, int job, int t, char* SM) {
  int lane = t & 63, w = t >> 6;
  int quad = lane >> 4, l16 = lane & 15;
  int nb = job & 7, mb = (job >> 3) & 7, ks = job >> 6;
  f32x4 acc[2][2];
  gemm64(A.obuf, A.w_projT, 512, nb, mb, ks * 128, 128, SM, t, acc);
  int wm = (w >> 1) * 32, wn = (w & 1) * 32;
#pragma unroll
  for (int mt = 0; mt < 2; ++mt)
#pragma unroll
    for (int rr = 0; rr < 4; ++rr) {
      int m = mb * 64 + wm + mt * 16 + quad * 4 + rr;
#pragma unroll
      for (int nt = 0; nt < 2; ++nt) {
        int n = nb * 64 + wn + nt * 16 + l16;
        A.part[(size_t)ks * 262144 + (size_t)m * 512 + n] = acc[mt][nt][rr];
      }
    }
}

__device__ void phase8(const AllArgs& A, int job, int t, char* SM) {
  epi_ln_body(A, job, t, 4, A.b_proj, A.x1, A.ln2_g, A.ln2_b, A.xa, A.ln2buf, SM);
}

// ---------------- P9: fc1 GEMM single-pass + gelu (256 jobs) ----------------
__device__ void phase9(const AllArgs& A, int job, int t, char* SM) {
  int lane = t & 63, w = t >> 6;
  int quad = lane >> 4, l16 = lane & 15;
  int nb = job & 31, mb = job >> 5;
  f32x4 acc[2][2];
  gemm64(A.ln2buf, A.w_fc1T, 512, nb, mb, 0, 512, SM, t, acc);
  int wm = (w >> 1) * 32, wn = (w & 1) * 32;
#pragma unroll
  for (int mt = 0; mt < 2; ++mt)
#pragma unroll
    for (int rr = 0; rr < 4; ++rr) {
      int m = mb * 64 + wm + mt * 16 + quad * 4 + rr;
#pragma unroll
      for (int nt = 0; nt < 2; ++nt) {
        int n = nb * 64 + wn + nt * 16 + l16;
        A.hfc[(size_t)m * 2048 + n] = f2b(gelu_f(acc[mt][nt][rr] + A.b_fc1[n]));
      }
    }
}

// ---------------- P10: fc2 GEMM split-K=4 (256 jobs) ----------------
__device__ void phase10(const AllArgs& A, int job, int t, char* SM) {
  int lane = t & 63, w = t >> 6;
  int quad = lane >> 4, l16 = lane & 15;
  int nb = job & 7, mb = (job >> 3) & 7, ks = job >> 6;
  f32x4 acc[2][2];
  gemm64(A.hfc, A.w_fc2T, 2048, nb, mb, ks * 512, 512, SM, t, acc);
  int wm = (w >> 1) * 32, wn = (w & 1) * 32;
#pragma unroll
  for (int mt = 0; mt < 2; ++mt)
#pragma unroll
    for (int rr = 0; rr < 4; ++rr) {
      int m = mb * 64 + wm + mt * 16 + quad * 4 + rr;
#pragma unroll
      for (int nt = 0; nt < 2; ++nt) {
        int n = nb * 64 + wn + nt * 16 + l16;
        A.part[(size_t)ks * 262144 + (size_t)m * 512 + n] = acc[mt][nt][rr];
      }
    }
}

// ---------------- P11: final epilogue (1024 jobs) ----------------
__device__ void phase11(const AllArgs& A, int job, int t, char* SM) {
  int idx = job * 256 + t;
  float a = A.part[idx] + A.part[262144 + idx] + A.part[2 * 262144 + idx] +
            A.part[3 * 262144 + idx];
  a += A.b_fc2[idx & 511];
  a += A.xa[idx];
  A.outf[idx] = a;
}

#define RUN_PHASE(FN, NJOBS)                                       \
  for (int job = blockIdx.x; job < (NJOBS); job += gridDim.x) {    \
    FN(A, job, t, SM);                                             \
    __syncthreads();                                               \
  }

// ---------------- cooperative mega-kernel ----------------
__global__ __launch_bounds__(256, 2) void k_all(AllArgs A) {
  cg::grid_group grid = cg::this_grid();
  __shared__ __align__(16) char SM[37440];
  int t = threadIdx.x;
  RUN_PHASE(phase0, 10240) grid.sync();
  RUN_PHASE(phase1, 1557) grid.sync();
  RUN_PHASE(phase2, 1024) grid.sync();
  RUN_PHASE(phase3, 1024) grid.sync();
  RUN_PHASE(phase4, 512) grid.sync();
  RUN_PHASE(phase5, 192) grid.sync();
  RUN_PHASE(phase6, 256) grid.sync();
  RUN_PHASE(phase7, 256) grid.sync();
  RUN_PHASE(phase8, 512) grid.sync();
  RUN_PHASE(phase9, 256) grid.sync();
  RUN_PHASE(phase10, 256) grid.sync();
  RUN_PHASE(phase11, 1024)
}

// ---------------- standalone fallback kernels (identical phase bodies) ----------------
#define MAKE_KP(NAME, FN, NJOBS)                                       \
  __global__ __launch_bounds__(256) void NAME(AllArgs A) {             \
    __shared__ __align__(16) char SM[37440];                           \
    int t = threadIdx.x;                                               \
    for (int job = blockIdx.x; job < (NJOBS); job += gridDim.x) {      \
      FN(A, job, t, SM);                                               \
      __syncthreads();                                                 \
    }                                                                  \
  }
MAKE_KP(k_p0, phase0, 10240)
MAKE_KP(k_p1, phase1, 1557)
MAKE_KP(k_p2, phase2, 1024)
MAKE_KP(k_p3, phase3, 1024)
MAKE_KP(k_p4, phase4, 512)
MAKE_KP(k_p5, phase5, 192)
MAKE_KP(k_p6, phase6, 256)
MAKE_KP(k_p7, phase7, 256)
MAKE_KP(k_p8, phase8, 512)
MAKE_KP(k_p9, phase9, 256)
MAKE_KP(k_p10, phase10, 256)
MAKE_KP(k_p11, phase11, 1024)

extern "C" void kernel_launch(void* const* d_in, const int* in_sizes, int n_in,
                              void* d_out, int out_size, void* d_ws, size_t ws_size,
                              hipStream_t stream) {
  AllArgs aa;
  aa.te = (const float*)d_in[0];
  aa.roi = (const float*)d_in[1];
  aa.img = (const float*)d_in[2];
  aa.g_off = (const float*)d_in[3];
  aa.b_off = (const float*)d_in[4];
  aa.w_off = (const float*)d_in[5];
  aa.off_bias = (const float*)d_in[6];
  aa.g_pg = (const float*)d_in[7];
  aa.b_pg = (const float*)d_in[8];
  aa.w_pg1 = (const float*)d_in[9];
  aa.b_pg1 = (const float*)d_in[10];
  aa.w_pg2 = (const float*)d_in[11];
  aa.b_pg2 = (const float*)d_in[12];
  aa.m_beta = (const float*)d_in[13];
  aa.s_beta = (const float*)d_in[14];
  aa.w_out = (const float*)d_in[15];
  aa.b_out = (const float*)d_in[16];
  aa.ln1_g = (const float*)d_in[17];
  aa.ln1_b = (const float*)d_in[18];
  aa.w_qkv = (const float*)d_in[19];
  aa.b_qkv = (const float*)d_in[20];
  aa.w_proj = (const float*)d_in[21];
  aa.b_proj = (const float*)d_in[22];
  aa.ln2_g = (const float*)d_in[23];
  aa.ln2_b = (const float*)d_in[24];
  aa.w_fc1 = (const float*)d_in[25];
  aa.b_fc1 = (const float*)d_in[26];
  aa.w_fc2 = (const float*)d_in[27];
  aa.b_fc2 = (const float*)d_in[28];

  char* ws = (char*)d_ws;
  // Region A: imgT [0, 64M); dead after P1; overlaid by transformer buffers (written P2+)
  aa.imgT = (bf16*)ws;
  char* ov = ws;
  aa.h2 = (bf16*)ov; ov += 9437184;
  aa.part = (float*)ov; ov += 16777216;   // 16 x 512 x 512 f32
  aa.x1 = (float*)ov; ov += 1048576;
  aa.xa = (float*)ov; ov += 1048576;
  aa.qkvf = (float*)ov; ov += 3145728;
  aa.ln1buf = (bf16*)ov; ov += 524288;
  aa.ln2buf = (bf16*)ov; ov += 524288;
  aa.obuf = (bf16*)ov; ov += 524288;
  aa.hfc = (bf16*)ov; ov += 2097152;
  // Region B: persistent tail
  char* tail = ws + 67108864;
  aa.Sbuf = (bf16*)tail; tail += 9437184;
  aa.tb16 = (bf16*)tail; tail += 131072;
  aa.meta_i = (int*)tail; tail += 294912;
  aa.meta_w = (float*)tail; tail += 294912;
  aa.pchunk = (bf16*)tail; tail += (size_t)NTOK * TOTC * 2;
  aa.w_outT = (bf16*)tail; tail += 9437184;
  aa.w_qkvT = (bf16*)tail; tail += 1572864;
  aa.w_projT = (bf16*)tail; tail += 524288;
  aa.w_fc1T = (bf16*)tail; tail += 2097152;
  aa.w_fc2T = (bf16*)tail; tail += 2097152;
  aa.outf = (float*)d_out;
  (void)ws_size;

  void* kp[] = {(void*)&aa};
  hipError_t err = hipLaunchCooperativeKernel((const void*)k_all, dim3(512), dim3(256),
                                              kp, 0, stream);
  if (err != hipSuccess) {
    // fallback: per-phase regular launches (identical math)
    k_p0<<<10240, 256, 0, stream>>>(aa);
    k_p1<<<1557, 256, 0, stream>>>(aa);
    k_p2<<<1024, 256, 0, stream>>>(aa);
    k_p3<<<1024, 256, 0, stream>>>(aa);
    k_p4<<<512, 256, 0, stream>>>(aa);
    k_p5<<<192, 256, 0, stream>>>(aa);
    k_p6<<<256, 256, 0, stream>>>(aa);
    k_p7<<<256, 256, 0, stream>>>(aa);
    k_p8<<<512, 256, 0, stream>>>(aa);
    k_p9<<<256, 256, 0, stream>>>(aa);
    k_p10<<<256, 256, 0, stream>>>(aa);
    k_p11<<<1024, 256, 0, stream>>>(aa);
  }
}